// Round 3
// baseline (766.344 us; speedup 1.0000x reference)
//
#include <hip/hip_runtime.h>
#include <math.h>

#define DD   120
#define KPAD 128
#define KP   136          // LDS row stride (shorts): 272 B rows, 16B-aligned, bank-floor-optimal
#define MT   64           // points per block
#define NTHR 512          // 8 waves: 4 M-groups x 2 N-halves
#define HASH_MASK 1048575LL
#define MODT 201

typedef short  short8  __attribute__((ext_vector_type(8)));
typedef float  floatx4 __attribute__((ext_vector_type(4)));

__device__ __forceinline__ unsigned short f2b(float f) {
    __bf16 h = (__bf16)f;
    return __builtin_bit_cast(unsigned short, h);
}
__device__ __forceinline__ float b2f(unsigned short u) {
    unsigned int x = ((unsigned int)u) << 16;
    return __builtin_bit_cast(float, x);
}

// ---------------------------------------------------------------------------
// Weight layouts in workspace (bf16 [8][128][128], W^T i.e. [n'][k']):
//  mats 0,1,2 (td q,k,v) and 4,5,6 (sd q,k,v): N head-padded (n'=h*16+j, j<15),
//    K standard (k'=k<120, pad 0).
//  mats 3,7 (td out, sd out): N standard (n'<120, pad 0), K head-padded
//    (k'=h*16+j consumes attention-output layout).
// Biases: bp float [8][128], padded to match each mat's N layout.
// ---------------------------------------------------------------------------
__global__ __launch_bounds__(256)
void prep_weights(const float* __restrict__ td_w, const float* __restrict__ sd_w,
                  unsigned short* __restrict__ wt)
{
    int idx = blockIdx.x * 256 + threadIdx.x;   // 8*128*128
    int mat = idx >> 14;
    int n   = (idx >> 7) & 127;
    int k   = idx & 127;
    const float* src = (mat < 4) ? (td_w + mat * DD * DD) : (sd_w + (mat - 4) * DD * DD);
    float v = 0.f;
    if (mat == 3 || mat == 7) {           // out-proj: K head-padded, N std
        int hk = k >> 4, jk = k & 15;
        if (n < DD && jk < 15) v = src[(hk * 15 + jk) * DD + n];
    } else {                              // qkv: N head-padded, K std
        int h = n >> 4, j = n & 15;
        if (j < 15 && k < DD) v = src[k * DD + h * 15 + j];
    }
    wt[idx] = f2b(v);
}

__global__ __launch_bounds__(128)
void prep_bias(const float* __restrict__ td_b, const float* __restrict__ sd_b,
               float* __restrict__ bp)
{
    int idx = blockIdx.x * 128 + threadIdx.x;   // 8*128
    int mat = idx >> 7;
    int n   = idx & 127;
    const float* src = (mat < 4) ? (td_b + mat * DD) : (sd_b + (mat - 4) * DD);
    float v = 0.f;
    if (mat == 3 || mat == 7) {
        if (n < DD) v = src[n];
    } else {
        int h = n >> 4, j = n & 15;
        if (j < 15) v = src[h * 15 + j];
    }
    bp[idx] = v;
}

// k1t/v1t[t][n'] = (te[t]@W1/W2 + b)[head-padded n'], bf16 [201][128]
__global__ __launch_bounds__(128)
void prep_te(const float* __restrict__ temb, const float* __restrict__ td_w,
             const float* __restrict__ td_b,
             unsigned short* __restrict__ k1t, unsigned short* __restrict__ v1t)
{
    int t = blockIdx.x;
    int np = threadIdx.x;
    int h = np >> 4, j = np & 15;
    float a1 = 0.f, a2 = 0.f;
    if (j < 15) {
        int n = h * 15 + j;
        a1 = td_b[DD + n];
        a2 = td_b[2 * DD + n];
        const float* te = temb + t * DD;
        const float* w1 = td_w + 1 * DD * DD;
        const float* w2 = td_w + 2 * DD * DD;
        for (int k = 0; k < DD; k++) {
            float x = te[k];
            a1 = fmaf(x, w1[k * DD + n], a1);
            a2 = fmaf(x, w2[k * DD + n], a2);
        }
    }
    k1t[t * KPAD + np] = f2b(a1);
    v1t[t * KPAD + np] = f2b(a2);
}

// ---------------------------------------------------------------------------
// Swapped-operand GEMM: mfma(w_frag, act_frag) => D[row=n-sub][col=m-sub],
// so each lane holds 4 contiguous n for one point row -> ds_write_b64.
// Wave (mg,nh): rows mg*16..+15, cols nh*64..+63 (4 N-tiles, A-frags reused 4x).
// ---------------------------------------------------------------------------
__device__ __forceinline__ void gemm4(const unsigned short* IN,
                                      const unsigned short* __restrict__ W,
                                      const float* __restrict__ BP,
                                      unsigned short* OUT,
                                      int mg, int nh, int lm, int lq)
{
    short8 af[4];
    const unsigned short* abase = IN + (mg * 16 + lm) * KP + lq * 8;
#pragma unroll
    for (int ks = 0; ks < 4; ks++) af[ks] = *(const short8*)(abase + ks * 32);
#pragma unroll
    for (int nt = 0; nt < 4; nt++) {
        const unsigned short* wbase = W + (nh * 64 + nt * 16 + lm) * KPAD + lq * 8;
        floatx4 acc = {0.f, 0.f, 0.f, 0.f};
#pragma unroll
        for (int ks = 0; ks < 4; ks++) {
            short8 wf = *(const short8*)(wbase + ks * 32);
            acc = __builtin_amdgcn_mfma_f32_16x16x32_bf16(wf, af[ks], acc, 0, 0, 0);
        }
        int nc = nh * 64 + nt * 16 + lq * 4;
        float4 b4 = *(const float4*)(BP + nc);
        unsigned int lo = (unsigned)f2b(acc[0] + b4.x) | ((unsigned)f2b(acc[1] + b4.y) << 16);
        unsigned int hi = (unsigned)f2b(acc[2] + b4.z) | ((unsigned)f2b(acc[3] + b4.w) << 16);
        *(uint2*)(OUT + (mg * 16 + lm) * KP + nc) = make_uint2(lo, hi);
    }
}

__device__ __forceinline__ void gemm_final(const unsigned short* IN,
                                           const unsigned short* __restrict__ W,
                                           const float* __restrict__ BP,
                                           float* __restrict__ out,
                                           const int* s_valid, int pbase, int Mpts,
                                           int mg, int nh, int lm, int lq)
{
    short8 af[4];
    const unsigned short* abase = IN + (mg * 16 + lm) * KP + lq * 8;
#pragma unroll
    for (int ks = 0; ks < 4; ks++) af[ks] = *(const short8*)(abase + ks * 32);
    int row = mg * 16 + lm;
    int gp = pbase + row;
    int vmask = s_valid[row];
#pragma unroll
    for (int nt = 0; nt < 4; nt++) {
        const unsigned short* wbase = W + (nh * 64 + nt * 16 + lm) * KPAD + lq * 8;
        floatx4 acc = {0.f, 0.f, 0.f, 0.f};
#pragma unroll
        for (int ks = 0; ks < 4; ks++) {
            short8 wf = *(const short8*)(wbase + ks * 32);
            acc = __builtin_amdgcn_mfma_f32_16x16x32_bf16(wf, af[ks], acc, 0, 0, 0);
        }
        int nc = nh * 64 + nt * 16 + lq * 4;
        if (nc < DD && gp < Mpts) {
            float4 b4 = *(const float4*)(BP + nc);
            float4 o;
            o.x = vmask ? (acc[0] + b4.x) : 0.f;
            o.y = vmask ? (acc[1] + b4.y) : 0.f;
            o.z = vmask ? (acc[2] + b4.z) : 0.f;
            o.w = vmask ? (acc[3] + b4.w) : 0.f;
            *(float4*)(out + (size_t)gp * DD + nc) = o;
        }
    }
}

// 16-elem bf16 dot (head-dim padded to 16, pad entries are zero)
__device__ __forceinline__ float dot16u(const unsigned short* A_, const unsigned short* B_)
{
    float s = 0.f;
#pragma unroll
    for (int half = 0; half < 2; half++) {
        short8 a = *(const short8*)(A_ + half * 8);
        short8 b = *(const short8*)(B_ + half * 8);
#pragma unroll
        for (int i = 0; i < 8; i++)
            s = fmaf(b2f((unsigned short)a[i]), b2f((unsigned short)b[i]), s);
    }
    return s;
}

// dst[0..15] = p0*v0 + (1-p0)*v1  (bf16 in/out, vectorized uint4)
__device__ __forceinline__ void comb16(unsigned short* dst, const unsigned short* v0,
                                       const unsigned short* v1, float p0)
{
    float q0 = 1.f - p0;
#pragma unroll
    for (int half = 0; half < 2; half++) {
        short8 a = *(const short8*)(v0 + half * 8);
        short8 b = *(const short8*)(v1 + half * 8);
        unsigned int w[4];
#pragma unroll
        for (int q = 0; q < 4; q++) {
            float lo = p0 * b2f((unsigned short)a[2 * q])     + q0 * b2f((unsigned short)b[2 * q]);
            float hi = p0 * b2f((unsigned short)a[2 * q + 1]) + q0 * b2f((unsigned short)b[2 * q + 1]);
            w[q] = (unsigned)f2b(lo) | ((unsigned)f2b(hi) << 16);
        }
        *(uint4*)(dst + half * 8) = make_uint4(w[0], w[1], w[2], w[3]);
    }
}

__global__ __launch_bounds__(NTHR, 4)   // 4 waves/EU => 2 blocks/CU
void voxel_mfma_kernel(const float* __restrict__ pts,
                       const int* __restrict__ times,
                       const int* __restrict__ vox_buf,
                       const float* __restrict__ stat_f,
                       const float* __restrict__ dyn_f,
                       const unsigned short* __restrict__ wt,
                       const float* __restrict__ bp,
                       const unsigned short* __restrict__ k1t,
                       const unsigned short* __restrict__ v1t,
                       float* __restrict__ out,
                       int Mpts)
{
    __shared__ __align__(16) unsigned short LA[MT * KP];
    __shared__ __align__(16) unsigned short LB[MT * KP];
    __shared__ __align__(16) unsigned short LC[MT * KP];
    __shared__ __align__(16) unsigned short LD[MT * KP];
    __shared__ float sc_p0[MT][8];
    __shared__ float sc_s0[MT][8];
    __shared__ int s_vi[MT];
    __shared__ int s_valid[MT];
    __shared__ int s_ti[MT];

    const int tid  = threadIdx.x;
    const int lane = tid & 63;
    const int lm   = lane & 15;
    const int lq   = lane >> 4;
    const int wid  = tid >> 6;
    const int mg   = wid >> 1;      // M-group (16 rows)
    const int nh   = wid & 1;       // N-half (64 cols)
    const int pbase = blockIdx.x * MT;
    const float scale = 0.2581988897471611f;  // 1/sqrt(15)

    // ---- P0a: per-point meta ----------------------------------------------
    if (tid < MT) {
        int p = pbase + tid;
        int vi = 0, valid = 0, ti = 0;
        if (p < Mpts) {
            float x = pts[3 * p + 0];
            float y = pts[3 * p + 1];
            float z = pts[3 * p + 2];
            long long gx = (long long)floorf(x / 0.1f);
            long long gy = (long long)floorf(y / 0.1f);
            long long gz = (long long)floorf(z / 0.1f);
            long long hh = (gx * 73856093LL + gy * 19349669LL + gz * 83492791LL) & HASH_MASK;
            int v = vox_buf[(int)hh];
            valid = (v >= 0) ? 1 : 0;
            vi = (v >= 0) ? v : 0;
            ti = times[p] % MODT;
        }
        s_vi[tid] = vi; s_valid[tid] = valid; s_ti[tid] = ti;
    }
    __syncthreads();

    // ---- P0b: gather df -> LA (bf16, std K, zero pad cols 120..127) -------
    for (int i = tid; i < MT * 32; i += NTHR) {
        int p = i >> 5, f = i & 31;
        if (f < 30) {
            float4 v = *(const float4*)(dyn_f + (size_t)s_vi[p] * DD + f * 4);
            unsigned int lo = (unsigned)f2b(v.x) | ((unsigned)f2b(v.y) << 16);
            unsigned int hi = (unsigned)f2b(v.z) | ((unsigned)f2b(v.w) << 16);
            *(uint2*)(LA + p * KP + f * 4) = make_uint2(lo, hi);
        } else if (f == 30) {
            *(uint4*)(LA + p * KP + 120) = make_uint4(0u, 0u, 0u, 0u);
        }
    }
    __syncthreads();

    // ---- P1: Q,K0,V0 = df @ tdW_{q,k,v}  -> LB,LC,LD ----------------------
    gemm4(LA, wt + 0 * 16384, bp + 0 * 128, LB, mg, nh, lm, lq);
    gemm4(LA, wt + 1 * 16384, bp + 1 * 128, LC, mg, nh, lm, lq);
    gemm4(LA, wt + 2 * 16384, bp + 2 * 128, LD, mg, nh, lm, lq);
    __syncthreads();

    // ---- P2: attn1 scores (k1 from global table); gather sf -> LA ---------
    {
        int p = tid >> 3, h = tid & 7;
        const unsigned short* qp  = LB + p * KP + h * 16;
        const unsigned short* k0p = LC + p * KP + h * 16;
        const unsigned short* k1p = k1t + s_ti[p] * KPAD + h * 16;
        float s0 = dot16u(qp, k0p) * scale;
        float s1 = dot16u(qp, k1p) * scale;
        sc_p0[p][h] = 1.f / (1.f + expf(s1 - s0));
    }
    for (int i = tid; i < MT * 32; i += NTHR) {
        int p = i >> 5, f = i & 31;
        if (f < 30) {
            float4 v = *(const float4*)(stat_f + (size_t)s_vi[p] * DD + f * 4);
            unsigned int lo = (unsigned)f2b(v.x) | ((unsigned)f2b(v.y) << 16);
            unsigned int hi = (unsigned)f2b(v.z) | ((unsigned)f2b(v.w) << 16);
            *(uint2*)(LA + p * KP + f * 4) = make_uint2(lo, hi);
        } else if (f == 30) {
            *(uint4*)(LA + p * KP + 120) = make_uint4(0u, 0u, 0u, 0u);
        }
    }
    __syncthreads();

    // ---- P3: attn1 combine: o1 = p0*V0 + (1-p0)*v1t -> LC -----------------
    {
        int p = tid >> 3, sg = tid & 7;
        comb16(LC + p * KP + sg * 16, LD + p * KP + sg * 16,
               v1t + s_ti[p] * KPAD + sg * 16, sc_p0[p][sg]);
    }
    __syncthreads();

    // ---- P4: cond = o1 @ tdW_out -> LB (std N) -----------------------------
    gemm4(LC, wt + 3 * 16384, bp + 3 * 128, LB, mg, nh, lm, lq);
    __syncthreads();

    // ---- P5: Qs = sf@sdWq -> LD; K0s = sf@sdWk -> LC -----------------------
    gemm4(LA, wt + 4 * 16384, bp + 4 * 128, LD, mg, nh, lm, lq);
    gemm4(LA, wt + 5 * 16384, bp + 5 * 128, LC, mg, nh, lm, lq);
    __syncthreads();

    // ---- P6: s0 = Qs.K0s ---------------------------------------------------
    {
        int p = tid >> 3, h = tid & 7;
        sc_s0[p][h] = dot16u(LD + p * KP + h * 16, LC + p * KP + h * 16) * scale;
    }
    __syncthreads();

    // ---- P7: K1s = cond@sdWk -> LC -----------------------------------------
    gemm4(LB, wt + 5 * 16384, bp + 5 * 128, LC, mg, nh, lm, lq);
    __syncthreads();

    // ---- P8: s1 = Qs.K1s; p0 -----------------------------------------------
    {
        int p = tid >> 3, h = tid & 7;
        float s1 = dot16u(LD + p * KP + h * 16, LC + p * KP + h * 16) * scale;
        sc_p0[p][h] = 1.f / (1.f + expf(s1 - sc_s0[p][h]));
    }
    __syncthreads();

    // ---- P9: V0s = sf@sdWv -> LD; V1s = cond@sdWv -> LC --------------------
    gemm4(LA, wt + 6 * 16384, bp + 6 * 128, LD, mg, nh, lm, lq);
    gemm4(LB, wt + 6 * 16384, bp + 6 * 128, LC, mg, nh, lm, lq);
    __syncthreads();

    // ---- P10: o2 = p0*V0s + (1-p0)*V1s -> LA -------------------------------
    {
        int p = tid >> 3, sg = tid & 7;
        comb16(LA + p * KP + sg * 16, LD + p * KP + sg * 16,
               LC + p * KP + sg * 16, sc_p0[p][sg]);
    }
    __syncthreads();

    // ---- P11: out = o2 @ sdW_out + b, masked -------------------------------
    gemm_final(LA, wt + 7 * 16384, bp + 7 * 128, out, s_valid, pbase, Mpts,
               mg, nh, lm, lq);
}

extern "C" void kernel_launch(void* const* d_in, const int* in_sizes, int n_in,
                              void* d_out, int out_size, void* d_ws, size_t ws_size,
                              hipStream_t stream) {
    const float* pts   = (const float*)d_in[0];
    const int*   times = (const int*)d_in[1];
    const int*   vox   = (const int*)d_in[2];
    const float* statf = (const float*)d_in[3];
    const float* dynf  = (const float*)d_in[4];
    const float* temb  = (const float*)d_in[5];
    const float* td_w  = (const float*)d_in[6];
    const float* td_b  = (const float*)d_in[7];
    const float* sd_w  = (const float*)d_in[8];
    const float* sd_b  = (const float*)d_in[9];

    unsigned short* wt  = (unsigned short*)d_ws;            // 8*128*128 bf16 = 256 KB
    float*          bpf = (float*)(wt + 8 * 128 * 128);     // 8*128 f32 = 4 KB
    unsigned short* k1t = (unsigned short*)(bpf + 8 * 128); // 201*128 bf16
    unsigned short* v1t = k1t + 201 * 128;

    prep_weights<<<512, 256, 0, stream>>>(td_w, sd_w, wt);
    prep_bias<<<8, 128, 0, stream>>>(td_b, sd_b, bpf);
    prep_te<<<201, 128, 0, stream>>>(temb, td_w, td_b, k1t, v1t);

    int Mpts = in_sizes[0] / 3;
    int blocks = (Mpts + MT - 1) / MT;
    voxel_mfma_kernel<<<blocks, NTHR, 0, stream>>>(
        pts, times, vox, statf, dynf, wt, bpf, k1t, v1t,
        (float*)d_out, Mpts);
}